// Round 1
// baseline (2675.161 us; speedup 1.0000x reference)
//
#include <hip/hip_runtime.h>

// COO SpMM: out[row[e], :] += values[e] * b[col[e], :]   (d = 128, f32)
//
// Round 1 design: edge-parallel with float atomics.
//  - 32 lanes per edge, each lane owns a float4 chunk of d=128.
//  - b[col] gather is coalesced (512 B per edge across 32 lanes).
//  - out accumulation via atomicAdd (device scope, correct across XCDs).
//  - d_out zeroed at the start of every launch (harness poisons it).

#define DIM 128

__global__ __launch_bounds__(256) void spmm_atomic_kernel(
    const int*   __restrict__ rows,
    const int*   __restrict__ cols,
    const float* __restrict__ vals,
    const float* __restrict__ b,
    float*       __restrict__ out,
    int E)
{
    long long t = (long long)blockIdx.x * blockDim.x + threadIdx.x;
    int e = (int)(t >> 5);          // 32 lanes per edge
    if (e >= E) return;
    int j = ((int)t & 31) * 4;      // float4 chunk within the row

    int   r = rows[e];
    int   c = cols[e];
    float v = vals[e];

    const float4 bv = *reinterpret_cast<const float4*>(b + (size_t)c * DIM + j);
    float* o = out + (size_t)r * DIM + j;

    atomicAdd(o + 0, v * bv.x);
    atomicAdd(o + 1, v * bv.y);
    atomicAdd(o + 2, v * bv.z);
    atomicAdd(o + 3, v * bv.w);
}

extern "C" void kernel_launch(void* const* d_in, const int* in_sizes, int n_in,
                              void* d_out, int out_size, void* d_ws, size_t ws_size,
                              hipStream_t stream)
{
    const int*   indices = (const int*)d_in[0];    // [2, E] row-major: rows then cols
    const float* vals    = (const float*)d_in[1];  // [E]
    const float* b       = (const float*)d_in[2];  // [N, 128]
    float*       out     = (float*)d_out;          // [N, 128]

    const int E = in_sizes[1];
    const int*   rows = indices;
    const int*   cols = indices + E;

    // Harness poisons d_out with 0xAA and does not re-zero between replays.
    hipMemsetAsync(d_out, 0, (size_t)out_size * sizeof(float), stream);

    const long long total = (long long)E * 32;   // 32 lanes per edge
    const int block = 256;
    const int grid  = (int)((total + block - 1) / block);

    spmm_atomic_kernel<<<grid, block, 0, stream>>>(rows, cols, vals, b, out, E);
}

// Round 3
// 332.412 us; speedup vs baseline: 8.0477x; 8.0477x over previous
//
#include <hip/hip_runtime.h>

// COO SpMM: out[row[e], :] += values[e] * b[col[e], :]   (d = 128, f32)
//
// Round 3 (= round 2 resubmit after infra failure): CSR build in d_ws, then
// row-parallel register accumulation (zero float atomics). Phases:
//   1. count:    counts[row[e]]++                (int atomics, L2-resident)
//   2. scan:     exclusive prefix sum -> offsets (3 small kernels)
//   3. scatter:  pairs[pos++] = {col, val}       (packed 8B)
//   4. accum:    one wave per row, float2/lane, write out once
// Falls back to the round-1 atomic kernel (proven, 2675 us) if ws too small.

#define DIM 128

// ---------------- fallback: edge-parallel atomics ----------------
__global__ __launch_bounds__(256) void spmm_atomic_kernel(
    const int* __restrict__ rows, const int* __restrict__ cols,
    const float* __restrict__ vals, const float* __restrict__ b,
    float* __restrict__ out, int E)
{
    long long t = (long long)blockIdx.x * blockDim.x + threadIdx.x;
    int e = (int)(t >> 5);
    if (e >= E) return;
    int j = ((int)t & 31) * 4;
    int r = rows[e]; int c = cols[e]; float v = vals[e];
    const float4 bv = *reinterpret_cast<const float4*>(b + (size_t)c * DIM + j);
    float* o = out + (size_t)r * DIM + j;
    atomicAdd(o + 0, v * bv.x);
    atomicAdd(o + 1, v * bv.y);
    atomicAdd(o + 2, v * bv.z);
    atomicAdd(o + 3, v * bv.w);
}

// ---------------- phase 1: histogram ----------------
__global__ __launch_bounds__(256) void count_kernel(
    const int* __restrict__ rows, int* __restrict__ counts, int E)
{
    for (int e = blockIdx.x * blockDim.x + threadIdx.x; e < E;
         e += gridDim.x * blockDim.x)
        atomicAdd(&counts[rows[e]], 1);
}

// ---------------- phase 2: scan (3 kernels) ----------------
__global__ __launch_bounds__(256) void block_sums_kernel(
    const int* __restrict__ counts, int* __restrict__ bsums, int N)
{
    __shared__ int tmp[256];
    int t = threadIdx.x;
    int i = blockIdx.x * 256 + t;
    tmp[t] = (i < N) ? counts[i] : 0;
    __syncthreads();
    for (int s = 128; s > 0; s >>= 1) {
        if (t < s) tmp[t] += tmp[t + s];
        __syncthreads();
    }
    if (t == 0) bsums[blockIdx.x] = tmp[0];
}

__global__ __launch_bounds__(512) void scan_bsums_kernel(
    int* __restrict__ bsums, int n)   // n <= 512, single block, exclusive in-place
{
    __shared__ int tmp[512];
    int t = threadIdx.x;
    int v = (t < n) ? bsums[t] : 0;
    tmp[t] = v;
    __syncthreads();
    for (int off = 1; off < 512; off <<= 1) {
        int x = (t >= off) ? tmp[t - off] : 0;
        __syncthreads();
        tmp[t] += x;
        __syncthreads();
    }
    if (t < n) bsums[t] = tmp[t] - v;   // exclusive
}

__global__ __launch_bounds__(256) void scan_chunk_kernel(
    const int* __restrict__ counts, const int* __restrict__ bsums,
    int* __restrict__ offsets, int N, int E)
{
    __shared__ int tmp[256];
    int t = threadIdx.x;
    int i = blockIdx.x * 256 + t;
    int v = (i < N) ? counts[i] : 0;
    tmp[t] = v;
    __syncthreads();
    for (int off = 1; off < 256; off <<= 1) {
        int x = (t >= off) ? tmp[t - off] : 0;
        __syncthreads();
        tmp[t] += x;
        __syncthreads();
    }
    int incl = tmp[t];
    int base = bsums[blockIdx.x];
    if (i < N) offsets[i] = base + incl - v;   // exclusive prefix
    if (i == N - 1) offsets[N] = E;
}

// ---------------- phase 3: scatter {col,val} ----------------
__global__ __launch_bounds__(256) void scatter_kernel(
    const int* __restrict__ rows, const int* __restrict__ cols,
    const float* __restrict__ vals, int* __restrict__ cursor,
    long long* __restrict__ pairs, int E)
{
    for (int e = blockIdx.x * blockDim.x + threadIdx.x; e < E;
         e += gridDim.x * blockDim.x) {
        int r = rows[e];
        int pos = atomicAdd(&cursor[r], 1);
        long long p = ((long long)__float_as_int(vals[e]) << 32) |
                      (unsigned int)cols[e];
        pairs[pos] = p;
    }
}

// ---------------- phase 4: row-parallel accumulate ----------------
__global__ __launch_bounds__(256) void accumulate_kernel(
    const int* __restrict__ offsets, const long long* __restrict__ pairs,
    const float* __restrict__ b, float* __restrict__ out, int N)
{
    int wid  = threadIdx.x >> 6;          // wave in block (0..3)
    int lane = threadIdx.x & 63;
    int r = blockIdx.x * 4 + wid;
    if (r >= N) return;

    int start = offsets[r];
    int end   = offsets[r + 1];

    float2 acc = make_float2(0.f, 0.f);
    const float* bl = b + lane * 2;

    int i = start;
    for (; i + 1 < end; i += 2) {          // unroll x2 for ILP
        long long p0 = pairs[i];
        long long p1 = pairs[i + 1];
        int   c0 = (int)(p0 & 0xffffffffLL);
        float v0 = __int_as_float((int)(p0 >> 32));
        int   c1 = (int)(p1 & 0xffffffffLL);
        float v1 = __int_as_float((int)(p1 >> 32));
        float2 b0 = *reinterpret_cast<const float2*>(bl + (size_t)c0 * DIM);
        float2 b1 = *reinterpret_cast<const float2*>(bl + (size_t)c1 * DIM);
        acc.x = fmaf(v0, b0.x, acc.x);
        acc.y = fmaf(v0, b0.y, acc.y);
        acc.x = fmaf(v1, b1.x, acc.x);
        acc.y = fmaf(v1, b1.y, acc.y);
    }
    if (i < end) {
        long long p0 = pairs[i];
        int   c0 = (int)(p0 & 0xffffffffLL);
        float v0 = __int_as_float((int)(p0 >> 32));
        float2 b0 = *reinterpret_cast<const float2*>(bl + (size_t)c0 * DIM);
        acc.x = fmaf(v0, b0.x, acc.x);
        acc.y = fmaf(v0, b0.y, acc.y);
    }
    *reinterpret_cast<float2*>(out + (size_t)r * DIM + lane * 2) = acc;
}

extern "C" void kernel_launch(void* const* d_in, const int* in_sizes, int n_in,
                              void* d_out, int out_size, void* d_ws, size_t ws_size,
                              hipStream_t stream)
{
    const int*   indices = (const int*)d_in[0];    // [2, E]: rows then cols
    const float* vals    = (const float*)d_in[1];  // [E]
    const float* b       = (const float*)d_in[2];  // [N, 128]
    float*       out     = (float*)d_out;          // [N, 128]

    const int E = in_sizes[1];
    const int N = in_sizes[2] / DIM;
    const int* rows = indices;
    const int* cols = indices + E;

    const int nblk = (N + 255) / 256;              // scan chunks

    // ws layout: [pairs E*8B][offsets (N+1)*4B][cursor N*4B][bsums nblk*4B]
    size_t pairs_bytes = (size_t)E * 8;
    size_t needed = pairs_bytes + ((size_t)(N + 1) + N + nblk) * 4;

    if (ws_size < needed || nblk > 512 || nblk < 1) {
        // fallback: round-1 atomic kernel (proven correct)
        hipMemsetAsync(d_out, 0, (size_t)out_size * sizeof(float), stream);
        const long long total = (long long)E * 32;
        const int grid = (int)((total + 255) / 256);
        spmm_atomic_kernel<<<grid, 256, 0, stream>>>(rows, cols, vals, b, out, E);
        return;
    }

    long long* pairs   = (long long*)d_ws;
    int*       offsets = (int*)((char*)d_ws + pairs_bytes);
    int*       cursor  = offsets + (N + 1);
    int*       bsums   = cursor + N;

    // phase 1: histogram into cursor (used as counts first)
    hipMemsetAsync(cursor, 0, (size_t)N * sizeof(int), stream);
    count_kernel<<<2048, 256, 0, stream>>>(rows, cursor, E);

    // phase 2: exclusive scan -> offsets
    block_sums_kernel<<<nblk, 256, 0, stream>>>(cursor, bsums, N);
    scan_bsums_kernel<<<1, 512, 0, stream>>>(bsums, nblk);
    scan_chunk_kernel<<<nblk, 256, 0, stream>>>(cursor, bsums, offsets, N, E);

    // phase 3: cursor <- offsets (running positions), then scatter pairs
    hipMemcpyAsync(cursor, offsets, (size_t)N * sizeof(int),
                   hipMemcpyDeviceToDevice, stream);
    scatter_kernel<<<2048, 256, 0, stream>>>(rows, cols, vals, cursor, pairs, E);

    // phase 4: one wave per row, register accumulate, single write
    accumulate_kernel<<<(N + 3) / 4, 256, 0, stream>>>(offsets, pairs, b, out, N);
}

// Round 4
// 215.726 us; speedup vs baseline: 12.4007x; 1.5409x over previous
//
#include <hip/hip_runtime.h>

// COO SpMM: out[row[e], :] += values[e] * b[col[e], :]   (d = 128, f32)
//
// Round 4: bucketed build. Rows are grouped into NB coarse buckets of 128
// rows. Pipeline:
//   k1 coarse_count : LDS-staged histogram of edges per bucket
//   k2 coarse_scan  : exclusive scan (1 block, NB <= 1024)
//   k3 partition    : chunked 2-pass counting partition; each block writes
//                     ~16-edge contiguous runs per bucket (coalesced lines)
//                     pairs[] entry packs val(32) | col(17)<<7 | rowlo(7)
//   k4 bucket_accum : 1 block/bucket; pairs -> LDS; fine per-row CSR built
//                     in LDS; wave-per-row register accumulate; single store
// Zero float atomics. out fully written by k4 (no memset needed).
// Fallback: round-1 atomic kernel if ws too small / NB > 1024.

#define DIM 128
#define RPB 128        // rows per coarse bucket
#define CAP 3072       // max edges staged in LDS per bucket (avg ~2048)
#define NCH 128        // partition chunk-blocks

// ---------------- fallback: edge-parallel atomics ----------------
__global__ __launch_bounds__(256) void spmm_atomic_kernel(
    const int* __restrict__ rows, const int* __restrict__ cols,
    const float* __restrict__ vals, const float* __restrict__ b,
    float* __restrict__ out, int E)
{
    long long t = (long long)blockIdx.x * blockDim.x + threadIdx.x;
    int e = (int)(t >> 5);
    if (e >= E) return;
    int j = ((int)t & 31) * 4;
    int r = rows[e]; int c = cols[e]; float v = vals[e];
    const float4 bv = *reinterpret_cast<const float4*>(b + (size_t)c * DIM + j);
    float* o = out + (size_t)r * DIM + j;
    atomicAdd(o + 0, v * bv.x);
    atomicAdd(o + 1, v * bv.y);
    atomicAdd(o + 2, v * bv.z);
    atomicAdd(o + 3, v * bv.w);
}

// ---------------- k1: coarse histogram (LDS-staged) ----------------
__global__ __launch_bounds__(256) void coarse_count_kernel(
    const int* __restrict__ rows, int* __restrict__ ccount, int E)
{
    __shared__ int hist[1024];
    for (int i = threadIdx.x; i < 1024; i += 256) hist[i] = 0;
    __syncthreads();
    int chunk = (E + NCH - 1) / NCH;
    int s = blockIdx.x * chunk;
    int e = min(s + chunk, E);
    for (int i = s + threadIdx.x; i < e; i += 256)
        atomicAdd(&hist[rows[i] >> 7], 1);
    __syncthreads();
    for (int i = threadIdx.x; i < 1024; i += 256)
        if (hist[i]) atomicAdd(&ccount[i], hist[i]);
}

// ---------------- k2: exclusive scan over NB <= 1024 buckets ----------------
__global__ __launch_bounds__(1024) void coarse_scan_kernel(
    const int* __restrict__ ccount, int* __restrict__ coffsets,
    int* __restrict__ ccursor, int NB, int E)
{
    __shared__ int tmp[1024];
    int t = threadIdx.x;
    int v = (t < NB) ? ccount[t] : 0;
    tmp[t] = v;
    __syncthreads();
    for (int off = 1; off < 1024; off <<= 1) {
        int x = (t >= off) ? tmp[t - off] : 0;
        __syncthreads();
        tmp[t] += x;
        __syncthreads();
    }
    int excl = tmp[t] - v;
    if (t < NB) { coffsets[t] = excl; ccursor[t] = excl; }
    if (t == NB - 1) coffsets[NB] = E;
}

// ---------------- k3: 2-pass chunked partition ----------------
__global__ __launch_bounds__(256) void partition_kernel(
    const int* __restrict__ rows, const int* __restrict__ cols,
    const float* __restrict__ vals, int* __restrict__ ccursor,
    unsigned long long* __restrict__ pairs, int E)
{
    __shared__ int hist[1024];
    __shared__ int base[1024];
    for (int i = threadIdx.x; i < 1024; i += 256) hist[i] = 0;
    __syncthreads();
    int chunk = (E + NCH - 1) / NCH;
    int s = blockIdx.x * chunk;
    int e = min(s + chunk, E);
    // pass 1: local histogram
    for (int i = s + threadIdx.x; i < e; i += 256)
        atomicAdd(&hist[rows[i] >> 7], 1);
    __syncthreads();
    // reserve contiguous global runs per bucket
    for (int i = threadIdx.x; i < 1024; i += 256) {
        int c = hist[i];
        base[i] = c ? atomicAdd(&ccursor[i], c) : 0;
        hist[i] = 0;                       // reuse as local rank cursor
    }
    __syncthreads();
    // pass 2: write packed edges into the reserved runs
    for (int i = s + threadIdx.x; i < e; i += 256) {
        int r = rows[i];
        int cb = r >> 7;
        int pos = base[cb] + atomicAdd(&hist[cb], 1);
        unsigned long long p =
            ((unsigned long long)(unsigned)__float_as_int(vals[i]) << 32) |
            (unsigned)((cols[i] << 7) | (r & (RPB - 1)));
        pairs[pos] = p;
    }
}

// ---------------- k4: per-bucket LDS fine-CSR + accumulate ----------------
__global__ __launch_bounds__(256) void bucket_accum_kernel(
    const int* __restrict__ coffsets,
    const unsigned long long* __restrict__ pairs,
    const float* __restrict__ b, float* __restrict__ out, int N)
{
    __shared__ unsigned long long ebuf[CAP];   // 24 KB
    __shared__ unsigned short     eord[CAP];   // 6 KB
    __shared__ int fcnt[RPB];                  // counts -> rank cursor
    __shared__ int foff[RPB + 1];              // fine CSR offsets
    __shared__ int stmp[RPB];                  // scan temp

    int cb = blockIdx.x;
    int cstart = coffsets[cb];
    int cend   = coffsets[cb + 1];
    int Mtot = cend - cstart;
    int M = min(Mtot, CAP);
    int t = threadIdx.x;

    // stage pairs into LDS (coalesced)
    for (int i = t; i < M; i += 256) ebuf[i] = pairs[cstart + i];
    if (t < RPB) fcnt[t] = 0;
    __syncthreads();

    // fine histogram over 128 local rows
    for (int i = t; i < M; i += 256)
        atomicAdd(&fcnt[(int)(ebuf[i] & (unsigned long long)(RPB - 1))], 1);
    __syncthreads();

    // inclusive scan of 128 counters (Hillis-Steele, all threads sync)
    if (t < RPB) stmp[t] = fcnt[t];
    __syncthreads();
    for (int off = 1; off < RPB; off <<= 1) {
        int x = 0;
        if (t < RPB && t >= off) x = stmp[t - off];
        __syncthreads();
        if (t < RPB) stmp[t] += x;
        __syncthreads();
    }
    if (t < RPB) {
        int excl = stmp[t] - fcnt[t];
        foff[t] = excl;
        fcnt[t] = excl;                        // rank cursor
    }
    if (t == RPB - 1) foff[RPB] = stmp[t];     // == M
    __syncthreads();

    // rank edges into eord (fine counting sort, indices only)
    for (int i = t; i < M; i += 256) {
        int rl = (int)(ebuf[i] & (unsigned long long)(RPB - 1));
        int pos = atomicAdd(&fcnt[rl], 1);
        eord[pos] = (unsigned short)i;
    }
    __syncthreads();

    // wave-per-row accumulate: wave w owns rows [w*32, w*32+32)
    int wid  = t >> 6;
    int lane = t & 63;
    const float* bl = b + lane * 2;

    for (int j = 0; j < RPB / 4 / 8; ++j) { /* placeholder guard, unused */ }

    for (int j = 0; j < 32; ++j) {
        int rl = wid * 32 + j;
        int rg = cb * RPB + rl;
        if (rg >= N) break;                    // uniform within wave
        float2 acc = make_float2(0.f, 0.f);
        int ks = foff[rl], ke = foff[rl + 1];
        int k = ks;
        for (; k + 1 < ke; k += 2) {           // 2x unroll for load ILP
            unsigned long long p0 = ebuf[eord[k]];
            unsigned long long p1 = ebuf[eord[k + 1]];
            int   c0 = (int)((unsigned)(p0 & 0xffffffffu) >> 7);
            float v0 = __int_as_float((int)(p0 >> 32));
            int   c1 = (int)((unsigned)(p1 & 0xffffffffu) >> 7);
            float v1 = __int_as_float((int)(p1 >> 32));
            float2 b0 = *reinterpret_cast<const float2*>(bl + (size_t)c0 * DIM);
            float2 b1 = *reinterpret_cast<const float2*>(bl + (size_t)c1 * DIM);
            acc.x = fmaf(v0, b0.x, acc.x);
            acc.y = fmaf(v0, b0.y, acc.y);
            acc.x = fmaf(v1, b1.x, acc.x);
            acc.y = fmaf(v1, b1.y, acc.y);
        }
        if (k < ke) {
            unsigned long long p0 = ebuf[eord[k]];
            int   c0 = (int)((unsigned)(p0 & 0xffffffffu) >> 7);
            float v0 = __int_as_float((int)(p0 >> 32));
            float2 b0 = *reinterpret_cast<const float2*>(bl + (size_t)c0 * DIM);
            acc.x = fmaf(v0, b0.x, acc.x);
            acc.y = fmaf(v0, b0.y, acc.y);
        }
        // overflow edges beyond CAP (statistically never; correctness path)
        for (int q = CAP; q < Mtot; ++q) {
            unsigned long long p = pairs[cstart + q];
            if ((int)(p & (unsigned long long)(RPB - 1)) == rl) {
                int   c = (int)((unsigned)(p & 0xffffffffu) >> 7);
                float v = __int_as_float((int)(p >> 32));
                float2 bv = *reinterpret_cast<const float2*>(bl + (size_t)c * DIM);
                acc.x = fmaf(v, bv.x, acc.x);
                acc.y = fmaf(v, bv.y, acc.y);
            }
        }
        *reinterpret_cast<float2*>(out + (size_t)rg * DIM + lane * 2) = acc;
    }
}

extern "C" void kernel_launch(void* const* d_in, const int* in_sizes, int n_in,
                              void* d_out, int out_size, void* d_ws, size_t ws_size,
                              hipStream_t stream)
{
    const int*   indices = (const int*)d_in[0];    // [2, E]: rows then cols
    const float* vals    = (const float*)d_in[1];  // [E]
    const float* b       = (const float*)d_in[2];  // [N, 128]
    float*       out     = (float*)d_out;          // [N, 128]

    const int E = in_sizes[1];
    const int N = in_sizes[2] / DIM;
    const int* rows = indices;
    const int* cols = indices + E;

    const int NB = (N + RPB - 1) / RPB;            // coarse buckets

    // ws layout: [pairs E*8B][ccount NB][coffsets NB+1][ccursor NB]
    size_t pairs_bytes = (size_t)E * 8;
    size_t needed = pairs_bytes + ((size_t)NB * 3 + 1) * 4;

    if (ws_size < needed || NB > 1024 || NB < 1 || E < 1) {
        hipMemsetAsync(d_out, 0, (size_t)out_size * sizeof(float), stream);
        if (E >= 1) {
            const long long total = (long long)E * 32;
            const int grid = (int)((total + 255) / 256);
            spmm_atomic_kernel<<<grid, 256, 0, stream>>>(rows, cols, vals, b, out, E);
        }
        return;
    }

    unsigned long long* pairs = (unsigned long long*)d_ws;
    int* ccount   = (int*)((char*)d_ws + pairs_bytes);
    int* coffsets = ccount + NB;
    int* ccursor  = coffsets + (NB + 1);

    hipMemsetAsync(ccount, 0, (size_t)NB * sizeof(int), stream);
    coarse_count_kernel<<<NCH, 256, 0, stream>>>(rows, ccount, E);
    coarse_scan_kernel<<<1, 1024, 0, stream>>>(ccount, coffsets, ccursor, NB, E);
    partition_kernel<<<NCH, 256, 0, stream>>>(rows, cols, vals, ccursor, pairs, E);
    bucket_accum_kernel<<<NB, 256, 0, stream>>>(coffsets, pairs, b, out, N);
}

// Round 5
// 200.413 us; speedup vs baseline: 13.3482x; 1.0764x over previous
//
#include <hip/hip_runtime.h>

// COO SpMM: out[row[e], :] += values[e] * b[col[e], :]   (d = 128, f32)
//
// Round 5: RPB=64 buckets (NB~1563 blocks, grid was occupancy limiter),
// register-staged pairs, LDS counting-sort into scol (byte offsets) + sval,
// 4x-unrolled gather loop (no dependent LDS chain).
//   k1 coarse_count : per-bucket histogram (LDS-staged, 2048 buckets max)
//   k2 coarse_scan  : exclusive scan, 1 block, 2 elems/thread (NB <= 2048)
//   k3 partition    : chunked 2-pass counting partition -> packed pairs
//                     pair = val(32) | col(17)<<6 | rowlo(6)
//   k4 bucket_accum : regs -> LDS sort -> wave-per-row accumulate -> store
// Zero float atomics. out fully written by k4.

#define DIM 128
#define RPB 64         // rows per bucket
#define CAP 2048       // max edges staged per bucket (mean 1024, std ~32)
#define NCH 128        // partition chunk-blocks
#define MAXNB 2048

// ---------------- fallback: edge-parallel atomics ----------------
__global__ __launch_bounds__(256) void spmm_atomic_kernel(
    const int* __restrict__ rows, const int* __restrict__ cols,
    const float* __restrict__ vals, const float* __restrict__ b,
    float* __restrict__ out, int E)
{
    long long t = (long long)blockIdx.x * blockDim.x + threadIdx.x;
    int e = (int)(t >> 5);
    if (e >= E) return;
    int j = ((int)t & 31) * 4;
    int r = rows[e]; int c = cols[e]; float v = vals[e];
    const float4 bv = *reinterpret_cast<const float4*>(b + (size_t)c * DIM + j);
    float* o = out + (size_t)r * DIM + j;
    atomicAdd(o + 0, v * bv.x);
    atomicAdd(o + 1, v * bv.y);
    atomicAdd(o + 2, v * bv.z);
    atomicAdd(o + 3, v * bv.w);
}

// ---------------- k1: coarse histogram ----------------
__global__ __launch_bounds__(256) void coarse_count_kernel(
    const int* __restrict__ rows, int* __restrict__ ccount, int E)
{
    __shared__ int hist[MAXNB];
    for (int i = threadIdx.x; i < MAXNB; i += 256) hist[i] = 0;
    __syncthreads();
    int chunk = (E + NCH - 1) / NCH;
    int s = blockIdx.x * chunk;
    int e = min(s + chunk, E);
    for (int i = s + threadIdx.x; i < e; i += 256)
        atomicAdd(&hist[rows[i] >> 6], 1);
    __syncthreads();
    for (int i = threadIdx.x; i < MAXNB; i += 256)
        if (hist[i]) atomicAdd(&ccount[i], hist[i]);
}

// ---------------- k2: exclusive scan, NB <= 2048, one block ----------------
__global__ __launch_bounds__(1024) void coarse_scan_kernel(
    const int* __restrict__ ccount, int* __restrict__ coffsets,
    int* __restrict__ ccursor, int NB, int E)
{
    __shared__ int s[1024];
    int t = threadIdx.x;
    int i0 = 2 * t, i1 = 2 * t + 1;
    int a  = (i0 < NB) ? ccount[i0] : 0;
    int bb = (i1 < NB) ? ccount[i1] : 0;
    s[t] = a + bb;
    __syncthreads();
    for (int off = 1; off < 1024; off <<= 1) {
        int x = (t >= off) ? s[t - off] : 0;
        __syncthreads();
        s[t] += x;
        __syncthreads();
    }
    int excl = s[t] - (a + bb);
    if (i0 < NB) { coffsets[i0] = excl;     ccursor[i0] = excl; }
    if (i1 < NB) { coffsets[i1] = excl + a; ccursor[i1] = excl + a; }
    if (t == 0) coffsets[NB] = E;
}

// ---------------- k3: 2-pass chunked partition ----------------
__global__ __launch_bounds__(256) void partition_kernel(
    const int* __restrict__ rows, const int* __restrict__ cols,
    const float* __restrict__ vals, int* __restrict__ ccursor,
    unsigned long long* __restrict__ pairs, int E)
{
    __shared__ int hist[MAXNB];
    __shared__ int base[MAXNB];
    for (int i = threadIdx.x; i < MAXNB; i += 256) hist[i] = 0;
    __syncthreads();
    int chunk = (E + NCH - 1) / NCH;
    int s = blockIdx.x * chunk;
    int e = min(s + chunk, E);
    for (int i = s + threadIdx.x; i < e; i += 256)
        atomicAdd(&hist[rows[i] >> 6], 1);
    __syncthreads();
    for (int i = threadIdx.x; i < MAXNB; i += 256) {
        int c = hist[i];
        base[i] = c ? atomicAdd(&ccursor[i], c) : 0;
        hist[i] = 0;                       // reuse as local rank cursor
    }
    __syncthreads();
    for (int i = s + threadIdx.x; i < e; i += 256) {
        int r = rows[i];
        int cb = r >> 6;
        int pos = base[cb] + atomicAdd(&hist[cb], 1);
        unsigned long long p =
            ((unsigned long long)(unsigned)__float_as_int(vals[i]) << 32) |
            (unsigned)((cols[i] << 6) | (r & (RPB - 1)));
        pairs[pos] = p;
    }
}

// ---------------- k4: reg-staged LDS counting sort + accumulate ----------------
__global__ __launch_bounds__(256) void bucket_accum_kernel(
    const int* __restrict__ coffsets,
    const unsigned long long* __restrict__ pairs,
    const float* __restrict__ b, float* __restrict__ out, int N)
{
    __shared__ int   scol[CAP];                // sorted byte offsets col*512
    __shared__ float sval[CAP];                // sorted values
    __shared__ int fcnt[RPB];
    __shared__ int foff[RPB + 1];
    __shared__ int stmp[RPB];

    int cb = blockIdx.x;
    int cstart = coffsets[cb];
    int Mtot = coffsets[cb + 1] - cstart;
    int M = min(Mtot, CAP);
    int t = threadIdx.x;

    // stage up to 8 pairs/thread into registers (static indexing)
    unsigned long long ep0 = 0, ep1 = 0, ep2 = 0, ep3 = 0,
                       ep4 = 0, ep5 = 0, ep6 = 0, ep7 = 0;
    {
        const unsigned long long* p = pairs + cstart;
        if (t           < M) ep0 = p[t];
        if (t +  256    < M) ep1 = p[t + 256];
        if (t +  512    < M) ep2 = p[t + 512];
        if (t +  768    < M) ep3 = p[t + 768];
        if (t + 1024    < M) ep4 = p[t + 1024];
        if (t + 1280    < M) ep5 = p[t + 1280];
        if (t + 1536    < M) ep6 = p[t + 1536];
        if (t + 1792    < M) ep7 = p[t + 1792];
    }
    if (t < RPB) fcnt[t] = 0;
    __syncthreads();

    // fine histogram (register pairs -> LDS counters)
    if (t           < M) atomicAdd(&fcnt[(int)(ep0 & (RPB - 1))], 1);
    if (t +  256    < M) atomicAdd(&fcnt[(int)(ep1 & (RPB - 1))], 1);
    if (t +  512    < M) atomicAdd(&fcnt[(int)(ep2 & (RPB - 1))], 1);
    if (t +  768    < M) atomicAdd(&fcnt[(int)(ep3 & (RPB - 1))], 1);
    if (t + 1024    < M) atomicAdd(&fcnt[(int)(ep4 & (RPB - 1))], 1);
    if (t + 1280    < M) atomicAdd(&fcnt[(int)(ep5 & (RPB - 1))], 1);
    if (t + 1536    < M) atomicAdd(&fcnt[(int)(ep6 & (RPB - 1))], 1);
    if (t + 1792    < M) atomicAdd(&fcnt[(int)(ep7 & (RPB - 1))], 1);
    __syncthreads();

    // inclusive scan of 64 counters
    if (t < RPB) stmp[t] = fcnt[t];
    __syncthreads();
    for (int off = 1; off < RPB; off <<= 1) {
        int x = 0;
        if (t < RPB && t >= off) x = stmp[t - off];
        __syncthreads();
        if (t < RPB) stmp[t] += x;
        __syncthreads();
    }
    if (t < RPB) {
        int excl = stmp[t] - fcnt[t];
        foff[t] = excl;
        fcnt[t] = excl;                        // rank cursor
    }
    if (t == RPB - 1) foff[RPB] = stmp[t];
    __syncthreads();

    // counting-sort write: sorted byte-offset + value
#define RANK_WRITE(EP, OFS)                                                  \
    if (t + (OFS) < M) {                                                     \
        unsigned lo = (unsigned)(EP & 0xffffffffu);                          \
        int pos = atomicAdd(&fcnt[(int)(lo & (RPB - 1))], 1);                \
        scol[pos] = (int)((lo & 0xffffffc0u) << 3);   /* col*512 */          \
        sval[pos] = __int_as_float((int)(EP >> 32));                         \
    }
    RANK_WRITE(ep0, 0)    RANK_WRITE(ep1, 256)  RANK_WRITE(ep2, 512)
    RANK_WRITE(ep3, 768)  RANK_WRITE(ep4, 1024) RANK_WRITE(ep5, 1280)
    RANK_WRITE(ep6, 1536) RANK_WRITE(ep7, 1792)
#undef RANK_WRITE
    __syncthreads();

    // wave-per-row accumulate: wave w owns rows [w*16, w*16+16)
    int wid  = t >> 6;
    int lane = t & 63;
    const char* bl = (const char*)b + lane * 8;

    for (int j = 0; j < RPB / 4; ++j) {
        int rl = wid * (RPB / 4) + j;
        int rg = cb * RPB + rl;
        if (rg >= N) break;                    // uniform within wave
        float2 acc = make_float2(0.f, 0.f);
        int ks = foff[rl], ke = foff[rl + 1];
        int k = ks;
        for (; k + 3 < ke; k += 4) {
            int o0 = scol[k],     o1 = scol[k + 1];
            int o2 = scol[k + 2], o3 = scol[k + 3];
            float v0 = sval[k],     v1 = sval[k + 1];
            float v2 = sval[k + 2], v3 = sval[k + 3];
            float2 b0 = *reinterpret_cast<const float2*>(bl + o0);
            float2 b1 = *reinterpret_cast<const float2*>(bl + o1);
            float2 b2 = *reinterpret_cast<const float2*>(bl + o2);
            float2 b3 = *reinterpret_cast<const float2*>(bl + o3);
            acc.x = fmaf(v0, b0.x, acc.x);  acc.y = fmaf(v0, b0.y, acc.y);
            acc.x = fmaf(v1, b1.x, acc.x);  acc.y = fmaf(v1, b1.y, acc.y);
            acc.x = fmaf(v2, b2.x, acc.x);  acc.y = fmaf(v2, b2.y, acc.y);
            acc.x = fmaf(v3, b3.x, acc.x);  acc.y = fmaf(v3, b3.y, acc.y);
        }
        for (; k < ke; ++k) {
            int o0 = scol[k];
            float v0 = sval[k];
            float2 b0 = *reinterpret_cast<const float2*>(bl + o0);
            acc.x = fmaf(v0, b0.x, acc.x);  acc.y = fmaf(v0, b0.y, acc.y);
        }
        // overflow edges beyond CAP (statistically never; correctness path)
        for (int q = CAP; q < Mtot; ++q) {
            unsigned long long p = pairs[cstart + q];
            if ((int)(p & (RPB - 1)) == rl) {
                unsigned lo = (unsigned)(p & 0xffffffffu);
                float v = __int_as_float((int)(p >> 32));
                float2 bv = *reinterpret_cast<const float2*>(
                    bl + (int)((lo & 0xffffffc0u) << 3));
                acc.x = fmaf(v, bv.x, acc.x);  acc.y = fmaf(v, bv.y, acc.y);
            }
        }
        *reinterpret_cast<float2*>(out + (size_t)rg * DIM + lane * 2) = acc;
    }
}

extern "C" void kernel_launch(void* const* d_in, const int* in_sizes, int n_in,
                              void* d_out, int out_size, void* d_ws, size_t ws_size,
                              hipStream_t stream)
{
    const int*   indices = (const int*)d_in[0];    // [2, E]: rows then cols
    const float* vals    = (const float*)d_in[1];  // [E]
    const float* b       = (const float*)d_in[2];  // [N, 128]
    float*       out     = (float*)d_out;          // [N, 128]

    const int E = in_sizes[1];
    const int N = in_sizes[2] / DIM;
    const int* rows = indices;
    const int* cols = indices + E;

    const int NB = (N + RPB - 1) / RPB;            // buckets

    size_t pairs_bytes = (size_t)E * 8;
    size_t needed = pairs_bytes + ((size_t)NB * 3 + 1) * 4;

    if (ws_size < needed || NB > MAXNB || NB < 1 || E < 1) {
        hipMemsetAsync(d_out, 0, (size_t)out_size * sizeof(float), stream);
        if (E >= 1) {
            const long long total = (long long)E * 32;
            const int grid = (int)((total + 255) / 256);
            spmm_atomic_kernel<<<grid, 256, 0, stream>>>(rows, cols, vals, b, out, E);
        }
        return;
    }

    unsigned long long* pairs = (unsigned long long*)d_ws;
    int* ccount   = (int*)((char*)d_ws + pairs_bytes);
    int* coffsets = ccount + NB;
    int* ccursor  = coffsets + (NB + 1);

    hipMemsetAsync(ccount, 0, (size_t)NB * sizeof(int), stream);
    coarse_count_kernel<<<NCH, 256, 0, stream>>>(rows, ccount, E);
    coarse_scan_kernel<<<1, 1024, 0, stream>>>(ccount, coffsets, ccursor, NB, E);
    partition_kernel<<<NCH, 256, 0, stream>>>(rows, cols, vals, ccursor, pairs, E);
    bucket_accum_kernel<<<NB, 256, 0, stream>>>(coffsets, pairs, b, out, N);
}

// Round 6
// 186.402 us; speedup vs baseline: 14.3516x; 1.0752x over previous
//
#include <hip/hip_runtime.h>

// COO SpMM: out[row[e], :] += values[e] * b[col[e], :]   (d = 128, f32)
//
// Round 6: RPB=64 buckets (partition keeps 8-edge coalesced runs), but k4
// goes to 512-thread blocks (8 waves x 8 rows) for ~full occupancy, and the
// gather loop is pad-to-4 + depth-2 software-pipelined (8 gathers in flight
// per wave, no remainder code).
//   k1 coarse_count : per-bucket histogram (LDS-staged), 256 chunk-blocks
//   k2 coarse_scan  : exclusive scan, 1 block, 2 elems/thread (NB <= 2048)
//   k3 partition    : chunked 2-pass counting partition -> packed pairs
//                     pair = val(32) | col(17)<<6 | rowlo(6)
//   k4 bucket_accum : regs -> LDS counting sort (padded to 4/row) ->
//                     pipelined wave-per-row accumulate -> single store
// Zero float atomics. out fully written by k4.

#define DIM 128
#define RPB 64         // rows per bucket
#define CAP 2048       // scol/sval entries (>= STAGE + 3*RPB)
#define STAGE 1792     // max real edges staged (mean 1024, sigma ~32)
#define NCH 256        // chunk-blocks for count/partition
#define MAXNB 2048

// ---------------- fallback: edge-parallel atomics ----------------
__global__ __launch_bounds__(256) void spmm_atomic_kernel(
    const int* __restrict__ rows, const int* __restrict__ cols,
    const float* __restrict__ vals, const float* __restrict__ b,
    float* __restrict__ out, int E)
{
    long long t = (long long)blockIdx.x * blockDim.x + threadIdx.x;
    int e = (int)(t >> 5);
    if (e >= E) return;
    int j = ((int)t & 31) * 4;
    int r = rows[e]; int c = cols[e]; float v = vals[e];
    const float4 bv = *reinterpret_cast<const float4*>(b + (size_t)c * DIM + j);
    float* o = out + (size_t)r * DIM + j;
    atomicAdd(o + 0, v * bv.x);
    atomicAdd(o + 1, v * bv.y);
    atomicAdd(o + 2, v * bv.z);
    atomicAdd(o + 3, v * bv.w);
}

// ---------------- k1: coarse histogram ----------------
__global__ __launch_bounds__(256) void coarse_count_kernel(
    const int* __restrict__ rows, int* __restrict__ ccount, int E)
{
    __shared__ int hist[MAXNB];
    for (int i = threadIdx.x; i < MAXNB; i += 256) hist[i] = 0;
    __syncthreads();
    int chunk = (E + NCH - 1) / NCH;
    int s = blockIdx.x * chunk;
    int e = min(s + chunk, E);
    for (int i = s + threadIdx.x; i < e; i += 256)
        atomicAdd(&hist[rows[i] >> 6], 1);
    __syncthreads();
    for (int i = threadIdx.x; i < MAXNB; i += 256)
        if (hist[i]) atomicAdd(&ccount[i], hist[i]);
}

// ---------------- k2: exclusive scan, NB <= 2048, one block ----------------
__global__ __launch_bounds__(1024) void coarse_scan_kernel(
    const int* __restrict__ ccount, int* __restrict__ coffsets,
    int* __restrict__ ccursor, int NB, int E)
{
    __shared__ int s[1024];
    int t = threadIdx.x;
    int i0 = 2 * t, i1 = 2 * t + 1;
    int a  = (i0 < NB) ? ccount[i0] : 0;
    int bb = (i1 < NB) ? ccount[i1] : 0;
    s[t] = a + bb;
    __syncthreads();
    for (int off = 1; off < 1024; off <<= 1) {
        int x = (t >= off) ? s[t - off] : 0;
        __syncthreads();
        s[t] += x;
        __syncthreads();
    }
    int excl = s[t] - (a + bb);
    if (i0 < NB) { coffsets[i0] = excl;     ccursor[i0] = excl; }
    if (i1 < NB) { coffsets[i1] = excl + a; ccursor[i1] = excl + a; }
    if (t == 0) coffsets[NB] = E;
}

// ---------------- k3: 2-pass chunked partition ----------------
__global__ __launch_bounds__(256) void partition_kernel(
    const int* __restrict__ rows, const int* __restrict__ cols,
    const float* __restrict__ vals, int* __restrict__ ccursor,
    unsigned long long* __restrict__ pairs, int E)
{
    __shared__ int hist[MAXNB];
    __shared__ int base[MAXNB];
    for (int i = threadIdx.x; i < MAXNB; i += 256) hist[i] = 0;
    __syncthreads();
    int chunk = (E + NCH - 1) / NCH;
    int s = blockIdx.x * chunk;
    int e = min(s + chunk, E);
    for (int i = s + threadIdx.x; i < e; i += 256)
        atomicAdd(&hist[rows[i] >> 6], 1);
    __syncthreads();
    for (int i = threadIdx.x; i < MAXNB; i += 256) {
        int c = hist[i];
        base[i] = c ? atomicAdd(&ccursor[i], c) : 0;
        hist[i] = 0;                       // reuse as local rank cursor
    }
    __syncthreads();
    for (int i = s + threadIdx.x; i < e; i += 256) {
        int r = rows[i];
        int cb = r >> 6;
        int pos = base[cb] + atomicAdd(&hist[cb], 1);
        unsigned long long p =
            ((unsigned long long)(unsigned)__float_as_int(vals[i]) << 32) |
            (unsigned)((cols[i] << 6) | (r & (RPB - 1)));
        pairs[pos] = p;
    }
}

// ---------------- k4: sort (pad-to-4) + pipelined accumulate ----------------
__global__ __launch_bounds__(512, 8) void bucket_accum_kernel(
    const int* __restrict__ coffsets,
    const unsigned long long* __restrict__ pairs,
    const float* __restrict__ b, float* __restrict__ out, int N)
{
    __shared__ int   scol[CAP];                // sorted byte offsets col*512
    __shared__ float sval[CAP];                // sorted values (pads = 0.0)
    __shared__ int fcnt[RPB];
    __shared__ int foff[RPB + 1];
    __shared__ int stmp[RPB];

    int cb = blockIdx.x;
    int cstart = coffsets[cb];
    int Mtot = coffsets[cb + 1] - cstart;
    int M = min(Mtot, STAGE);
    int t = threadIdx.x;

    // stage up to 4 pairs/thread into registers (static indexing)
    unsigned long long ep0 = 0, ep1 = 0, ep2 = 0, ep3 = 0;
    {
        const unsigned long long* p = pairs + cstart;
        if (t          < M) ep0 = p[t];
        if (t +  512   < M) ep1 = p[t + 512];
        if (t + 1024   < M) ep2 = p[t + 1024];
        if (t + 1536   < M) ep3 = p[t + 1536];
    }
    // zero pads target arrays + counters
    for (int i = t; i < CAP; i += 512) { scol[i] = 0; sval[i] = 0.0f; }
    if (t < RPB) fcnt[t] = 0;
    __syncthreads();

    // fine histogram
    if (t          < M) atomicAdd(&fcnt[(int)(ep0 & (RPB - 1))], 1);
    if (t +  512   < M) atomicAdd(&fcnt[(int)(ep1 & (RPB - 1))], 1);
    if (t + 1024   < M) atomicAdd(&fcnt[(int)(ep2 & (RPB - 1))], 1);
    if (t + 1536   < M) atomicAdd(&fcnt[(int)(ep3 & (RPB - 1))], 1);
    __syncthreads();

    // padded (to 4) inclusive scan of 64 counters
    int pc = 0;
    if (t < RPB) { pc = (fcnt[t] + 3) & ~3; stmp[t] = pc; }
    __syncthreads();
    for (int off = 1; off < RPB; off <<= 1) {
        int x = 0;
        if (t < RPB && t >= off) x = stmp[t - off];
        __syncthreads();
        if (t < RPB) stmp[t] += x;
        __syncthreads();
    }
    if (t < RPB) {
        int excl = stmp[t] - pc;
        foff[t] = excl;
        fcnt[t] = excl;                        // rank cursor (real entries)
    }
    if (t == RPB - 1) foff[RPB] = stmp[t];
    __syncthreads();

    // counting-sort write: sorted byte-offset + value; pads stay {0, 0.0}
#define RANK_WRITE(EP, OFS)                                                  \
    if (t + (OFS) < M) {                                                     \
        unsigned lo = (unsigned)(EP & 0xffffffffu);                          \
        int pos = atomicAdd(&fcnt[(int)(lo & (RPB - 1))], 1);                \
        scol[pos] = (int)((lo & 0xffffffc0u) << 3);   /* col*512 */          \
        sval[pos] = __int_as_float((int)(EP >> 32));                         \
    }
    RANK_WRITE(ep0, 0) RANK_WRITE(ep1, 512) RANK_WRITE(ep2, 1024) RANK_WRITE(ep3, 1536)
#undef RANK_WRITE
    __syncthreads();

    // wave-per-row accumulate: wave w owns rows [w*8, w*8+8)
    int wid  = t >> 6;                         // 0..7
    int lane = t & 63;
    const char* bl = (const char*)b + lane * 8;

    for (int j = 0; j < 8; ++j) {
        int rl = wid * 8 + j;
        int rg = cb * RPB + rl;
        if (rg >= N) break;                    // uniform within wave
        float2 acc = make_float2(0.f, 0.f);
        int ks = foff[rl], ke = foff[rl + 1];  // multiple-of-4 range
        if (ks < ke) {
            int   o0 = scol[ks],     o1 = scol[ks + 1];
            int   o2 = scol[ks + 2], o3 = scol[ks + 3];
            float v0 = sval[ks],     v1 = sval[ks + 1];
            float v2 = sval[ks + 2], v3 = sval[ks + 3];
            float2 c0 = *reinterpret_cast<const float2*>(bl + o0);
            float2 c1 = *reinterpret_cast<const float2*>(bl + o1);
            float2 c2 = *reinterpret_cast<const float2*>(bl + o2);
            float2 c3 = *reinterpret_cast<const float2*>(bl + o3);
            for (int k = ks + 4; k < ke; k += 4) {
                int   n0 = scol[k],     n1 = scol[k + 1];
                int   n2 = scol[k + 2], n3 = scol[k + 3];
                float w0 = sval[k],     w1 = sval[k + 1];
                float w2 = sval[k + 2], w3 = sval[k + 3];
                float2 d0 = *reinterpret_cast<const float2*>(bl + n0);
                float2 d1 = *reinterpret_cast<const float2*>(bl + n1);
                float2 d2 = *reinterpret_cast<const float2*>(bl + n2);
                float2 d3 = *reinterpret_cast<const float2*>(bl + n3);
                acc.x = fmaf(v0, c0.x, acc.x);  acc.y = fmaf(v0, c0.y, acc.y);
                acc.x = fmaf(v1, c1.x, acc.x);  acc.y = fmaf(v1, c1.y, acc.y);
                acc.x = fmaf(v2, c2.x, acc.x);  acc.y = fmaf(v2, c2.y, acc.y);
                acc.x = fmaf(v3, c3.x, acc.x);  acc.y = fmaf(v3, c3.y, acc.y);
                c0 = d0; c1 = d1; c2 = d2; c3 = d3;
                v0 = w0; v1 = w1; v2 = w2; v3 = w3;
            }
            acc.x = fmaf(v0, c0.x, acc.x);  acc.y = fmaf(v0, c0.y, acc.y);
            acc.x = fmaf(v1, c1.x, acc.x);  acc.y = fmaf(v1, c1.y, acc.y);
            acc.x = fmaf(v2, c2.x, acc.x);  acc.y = fmaf(v2, c2.y, acc.y);
            acc.x = fmaf(v3, c3.x, acc.x);  acc.y = fmaf(v3, c3.y, acc.y);
        }
        // overflow edges beyond STAGE (statistically never; correctness path)
        for (int q = STAGE; q < Mtot; ++q) {
            unsigned long long p = pairs[cstart + q];
            if ((int)(p & (RPB - 1)) == rl) {
                unsigned lo = (unsigned)(p & 0xffffffffu);
                float v = __int_as_float((int)(p >> 32));
                float2 bv = *reinterpret_cast<const float2*>(
                    bl + (int)((lo & 0xffffffc0u) << 3));
                acc.x = fmaf(v, bv.x, acc.x);  acc.y = fmaf(v, bv.y, acc.y);
            }
        }
        *reinterpret_cast<float2*>(out + (size_t)rg * DIM + lane * 2) = acc;
    }
}

extern "C" void kernel_launch(void* const* d_in, const int* in_sizes, int n_in,
                              void* d_out, int out_size, void* d_ws, size_t ws_size,
                              hipStream_t stream)
{
    const int*   indices = (const int*)d_in[0];    // [2, E]: rows then cols
    const float* vals    = (const float*)d_in[1];  // [E]
    const float* b       = (const float*)d_in[2];  // [N, 128]
    float*       out     = (float*)d_out;          // [N, 128]

    const int E = in_sizes[1];
    const int N = in_sizes[2] / DIM;
    const int* rows = indices;
    const int* cols = indices + E;

    const int NB = (N + RPB - 1) / RPB;            // buckets

    size_t pairs_bytes = (size_t)E * 8;
    size_t needed = pairs_bytes + ((size_t)NB * 3 + 1) * 4;

    if (ws_size < needed || NB > MAXNB || NB < 1 || E < 1) {
        hipMemsetAsync(d_out, 0, (size_t)out_size * sizeof(float), stream);
        if (E >= 1) {
            const long long total = (long long)E * 32;
            const int grid = (int)((total + 255) / 256);
            spmm_atomic_kernel<<<grid, 256, 0, stream>>>(rows, cols, vals, b, out, E);
        }
        return;
    }

    unsigned long long* pairs = (unsigned long long*)d_ws;
    int* ccount   = (int*)((char*)d_ws + pairs_bytes);
    int* coffsets = ccount + NB;
    int* ccursor  = coffsets + (NB + 1);

    hipMemsetAsync(ccount, 0, (size_t)NB * sizeof(int), stream);
    coarse_count_kernel<<<NCH, 256, 0, stream>>>(rows, ccount, E);
    coarse_scan_kernel<<<1, 1024, 0, stream>>>(ccount, coffsets, ccursor, NB, E);
    partition_kernel<<<NCH, 256, 0, stream>>>(rows, cols, vals, ccursor, pairs, E);
    bucket_accum_kernel<<<NB, 512, 0, stream>>>(coffsets, pairs, b, out, N);
}

// Round 9
// 180.584 us; speedup vs baseline: 14.8140x; 1.0322x over previous
//
#include <hip/hip_runtime.h>

// COO SpMM: out[row[e], :] += values[e] * b[col[e], :]   (d = 128, f32)
//
// Round 9 (= round 7 resubmit; rounds 7+8 hit dead-container infra failures
// before the kernel ever ran): k4 rebuilt for MLP.
//  - 256-thread blocks (4 waves x 16 rows), RPB=64 -> 8 blocks/CU resident,
//    1563 blocks in a single generation (no tail).
//  - rows padded to multiples of 8; {col_off=0, val=0} pads gather b[0]
//    (L1-resident) and contribute 0.
//  - 8-wide depth-2 software pipeline with sched_barrier(0) so the compiler
//    cannot sink the next-group gathers below the FMAs (round-6 failure:
//    VGPR=16 proved the pipeline was collapsed).
//  - scol/sval merged into int2 svec[] (one LDS read per edge).
// k1/k2/k3 unchanged from round 6.

#define DIM 128
#define RPB 64          // rows per bucket
#define STAGE 1792      // max real edges staged (mean 1024, sigma ~32) = 7*256
#define CAP (STAGE + 7 * RPB)   // 2240: worst-case pad-to-8
#define NCH 256         // chunk-blocks for count/partition
#define MAXNB 2048

// ---------------- fallback: edge-parallel atomics ----------------
__global__ __launch_bounds__(256) void spmm_atomic_kernel(
    const int* __restrict__ rows, const int* __restrict__ cols,
    const float* __restrict__ vals, const float* __restrict__ b,
    float* __restrict__ out, int E)
{
    long long t = (long long)blockIdx.x * blockDim.x + threadIdx.x;
    int e = (int)(t >> 5);
    if (e >= E) return;
    int j = ((int)t & 31) * 4;
    int r = rows[e]; int c = cols[e]; float v = vals[e];
    const float4 bv = *reinterpret_cast<const float4*>(b + (size_t)c * DIM + j);
    float* o = out + (size_t)r * DIM + j;
    atomicAdd(o + 0, v * bv.x);
    atomicAdd(o + 1, v * bv.y);
    atomicAdd(o + 2, v * bv.z);
    atomicAdd(o + 3, v * bv.w);
}

// ---------------- k1: coarse histogram ----------------
__global__ __launch_bounds__(256) void coarse_count_kernel(
    const int* __restrict__ rows, int* __restrict__ ccount, int E)
{
    __shared__ int hist[MAXNB];
    for (int i = threadIdx.x; i < MAXNB; i += 256) hist[i] = 0;
    __syncthreads();
    int chunk = (E + NCH - 1) / NCH;
    int s = blockIdx.x * chunk;
    int e = min(s + chunk, E);
    for (int i = s + threadIdx.x; i < e; i += 256)
        atomicAdd(&hist[rows[i] >> 6], 1);
    __syncthreads();
    for (int i = threadIdx.x; i < MAXNB; i += 256)
        if (hist[i]) atomicAdd(&ccount[i], hist[i]);
}

// ---------------- k2: exclusive scan, NB <= 2048, one block ----------------
__global__ __launch_bounds__(1024) void coarse_scan_kernel(
    const int* __restrict__ ccount, int* __restrict__ coffsets,
    int* __restrict__ ccursor, int NB, int E)
{
    __shared__ int s[1024];
    int t = threadIdx.x;
    int i0 = 2 * t, i1 = 2 * t + 1;
    int a  = (i0 < NB) ? ccount[i0] : 0;
    int bb = (i1 < NB) ? ccount[i1] : 0;
    s[t] = a + bb;
    __syncthreads();
    for (int off = 1; off < 1024; off <<= 1) {
        int x = (t >= off) ? s[t - off] : 0;
        __syncthreads();
        s[t] += x;
        __syncthreads();
    }
    int excl = s[t] - (a + bb);
    if (i0 < NB) { coffsets[i0] = excl;     ccursor[i0] = excl; }
    if (i1 < NB) { coffsets[i1] = excl + a; ccursor[i1] = excl + a; }
    if (t == 0) coffsets[NB] = E;
}

// ---------------- k3: 2-pass chunked partition ----------------
__global__ __launch_bounds__(256) void partition_kernel(
    const int* __restrict__ rows, const int* __restrict__ cols,
    const float* __restrict__ vals, int* __restrict__ ccursor,
    unsigned long long* __restrict__ pairs, int E)
{
    __shared__ int hist[MAXNB];
    __shared__ int base[MAXNB];
    for (int i = threadIdx.x; i < MAXNB; i += 256) hist[i] = 0;
    __syncthreads();
    int chunk = (E + NCH - 1) / NCH;
    int s = blockIdx.x * chunk;
    int e = min(s + chunk, E);
    for (int i = s + threadIdx.x; i < e; i += 256)
        atomicAdd(&hist[rows[i] >> 6], 1);
    __syncthreads();
    for (int i = threadIdx.x; i < MAXNB; i += 256) {
        int c = hist[i];
        base[i] = c ? atomicAdd(&ccursor[i], c) : 0;
        hist[i] = 0;                       // reuse as local rank cursor
    }
    __syncthreads();
    for (int i = s + threadIdx.x; i < e; i += 256) {
        int r = rows[i];
        int cb = r >> 6;
        int pos = base[cb] + atomicAdd(&hist[cb], 1);
        unsigned long long p =
            ((unsigned long long)(unsigned)__float_as_int(vals[i]) << 32) |
            (unsigned)((cols[i] << 6) | (r & (RPB - 1)));
        pairs[pos] = p;
    }
}

// ---------------- k4: sort (pad-to-8) + forced depth-2 pipeline ----------------
__global__ __launch_bounds__(256) void bucket_accum_kernel(
    const int* __restrict__ coffsets,
    const unsigned long long* __restrict__ pairs,
    const float* __restrict__ b, float* __restrict__ out, int N)
{
    __shared__ int2 svec[CAP];                 // {col*512, val_bits}; pads {0,0}
    __shared__ int fcnt[RPB];
    __shared__ int foff[RPB + 1];
    __shared__ int stmp[RPB];

    int cb = blockIdx.x;
    int cstart = coffsets[cb];
    int Mtot = coffsets[cb + 1] - cstart;
    int M = min(Mtot, STAGE);
    int t = threadIdx.x;

    // stage up to 7 pairs/thread into registers (static indexing)
    unsigned long long ep0 = 0, ep1 = 0, ep2 = 0, ep3 = 0, ep4 = 0, ep5 = 0, ep6 = 0;
    {
        const unsigned long long* p = pairs + cstart;
        if (t          < M) ep0 = p[t];
        if (t +  256   < M) ep1 = p[t + 256];
        if (t +  512   < M) ep2 = p[t + 512];
        if (t +  768   < M) ep3 = p[t + 768];
        if (t + 1024   < M) ep4 = p[t + 1024];
        if (t + 1280   < M) ep5 = p[t + 1280];
        if (t + 1536   < M) ep6 = p[t + 1536];
    }
    // zero svec (pads must be {0, 0.0}) + counters
    for (int i = t; i < CAP; i += 256) svec[i] = make_int2(0, 0);
    if (t < RPB) fcnt[t] = 0;
    __syncthreads();

    // fine histogram
    if (t          < M) atomicAdd(&fcnt[(int)(ep0 & (RPB - 1))], 1);
    if (t +  256   < M) atomicAdd(&fcnt[(int)(ep1 & (RPB - 1))], 1);
    if (t +  512   < M) atomicAdd(&fcnt[(int)(ep2 & (RPB - 1))], 1);
    if (t +  768   < M) atomicAdd(&fcnt[(int)(ep3 & (RPB - 1))], 1);
    if (t + 1024   < M) atomicAdd(&fcnt[(int)(ep4 & (RPB - 1))], 1);
    if (t + 1280   < M) atomicAdd(&fcnt[(int)(ep5 & (RPB - 1))], 1);
    if (t + 1536   < M) atomicAdd(&fcnt[(int)(ep6 & (RPB - 1))], 1);
    __syncthreads();

    // padded (to 8) inclusive scan of 64 counters
    int pc = 0;
    if (t < RPB) { pc = (fcnt[t] + 7) & ~7; stmp[t] = pc; }
    __syncthreads();
    for (int off = 1; off < RPB; off <<= 1) {
        int x = 0;
        if (t < RPB && t >= off) x = stmp[t - off];
        __syncthreads();
        if (t < RPB) stmp[t] += x;
        __syncthreads();
    }
    if (t < RPB) {
        int excl = stmp[t] - pc;
        foff[t] = excl;
        fcnt[t] = excl;                        // rank cursor (real entries)
    }
    if (t == RPB - 1) foff[RPB] = stmp[t];
    __syncthreads();

    // counting-sort write; pads stay {0, 0.0}
#define RANK_WRITE(EP, OFS)                                                  \
    if (t + (OFS) < M) {                                                     \
        unsigned lo = (unsigned)(EP & 0xffffffffu);                          \
        int pos = atomicAdd(&fcnt[(int)(lo & (RPB - 1))], 1);                \
        svec[pos] = make_int2((int)((lo & 0xffffffc0u) << 3),  /* col*512 */ \
                              (int)(EP >> 32));                              \
    }
    RANK_WRITE(ep0, 0)    RANK_WRITE(ep1, 256)  RANK_WRITE(ep2, 512)
    RANK_WRITE(ep3, 768)  RANK_WRITE(ep4, 1024) RANK_WRITE(ep5, 1280)
    RANK_WRITE(ep6, 1536)
#undef RANK_WRITE
    __syncthreads();

    // wave-per-row accumulate: wave w owns rows [w*16, w*16+16)
    int wid  = t >> 6;                         // 0..3
    int lane = t & 63;
    const char* bl = (const char*)b + lane * 8;

    for (int j = 0; j < 16; ++j) {
        int rl = wid * 16 + j;
        int rg = cb * RPB + rl;
        if (rg >= N) break;                    // uniform within wave
        float2 acc = make_float2(0.f, 0.f);
        int ks = foff[rl], ke = foff[rl + 1];  // multiple-of-8 range
        if (ks < ke) {
            // preload group (8 edges)
            int2 e0 = svec[ks],     e1 = svec[ks + 1];
            int2 e2 = svec[ks + 2], e3 = svec[ks + 3];
            int2 e4 = svec[ks + 4], e5 = svec[ks + 5];
            int2 e6 = svec[ks + 6], e7 = svec[ks + 7];
            float2 c0 = *reinterpret_cast<const float2*>(bl + e0.x);
            float2 c1 = *reinterpret_cast<const float2*>(bl + e1.x);
            float2 c2 = *reinterpret_cast<const float2*>(bl + e2.x);
            float2 c3 = *reinterpret_cast<const float2*>(bl + e3.x);
            float2 c4 = *reinterpret_cast<const float2*>(bl + e4.x);
            float2 c5 = *reinterpret_cast<const float2*>(bl + e5.x);
            float2 c6 = *reinterpret_cast<const float2*>(bl + e6.x);
            float2 c7 = *reinterpret_cast<const float2*>(bl + e7.x);
            for (int k = ks + 8; k < ke; k += 8) {
                // issue next group's gathers FIRST...
                int2 f0 = svec[k],     f1 = svec[k + 1];
                int2 f2 = svec[k + 2], f3 = svec[k + 3];
                int2 f4 = svec[k + 4], f5 = svec[k + 5];
                int2 f6 = svec[k + 6], f7 = svec[k + 7];
                float2 d0 = *reinterpret_cast<const float2*>(bl + f0.x);
                float2 d1 = *reinterpret_cast<const float2*>(bl + f1.x);
                float2 d2 = *reinterpret_cast<const float2*>(bl + f2.x);
                float2 d3 = *reinterpret_cast<const float2*>(bl + f3.x);
                float2 d4 = *reinterpret_cast<const float2*>(bl + f4.x);
                float2 d5 = *reinterpret_cast<const float2*>(bl + f5.x);
                float2 d6 = *reinterpret_cast<const float2*>(bl + f6.x);
                float2 d7 = *reinterpret_cast<const float2*>(bl + f7.x);
                // ...and forbid the compiler from sinking them below the FMAs
                __builtin_amdgcn_sched_barrier(0);
                float v;
                v = __int_as_float(e0.y); acc.x = fmaf(v, c0.x, acc.x); acc.y = fmaf(v, c0.y, acc.y);
                v = __int_as_float(e1.y); acc.x = fmaf(v, c1.x, acc.x); acc.y = fmaf(v, c1.y, acc.y);
                v = __int_as_float(e2.y); acc.x = fmaf(v, c2.x, acc.x); acc.y = fmaf(v, c2.y, acc.y);
                v = __int_as_float(e3.y); acc.x = fmaf(v, c3.x, acc.x); acc.y = fmaf(v, c3.y, acc.y);
                v = __int_as_float(e4.y); acc.x = fmaf(v, c4.x, acc.x); acc.y = fmaf(v, c4.y, acc.y);
                v = __int_as_float(e5.y); acc.x = fmaf(v, c5.x, acc.x); acc.y = fmaf(v, c5.y, acc.y);
                v = __int_as_float(e6.y); acc.x = fmaf(v, c6.x, acc.x); acc.y = fmaf(v, c6.y, acc.y);
                v = __int_as_float(e7.y); acc.x = fmaf(v, c7.x, acc.x); acc.y = fmaf(v, c7.y, acc.y);
                e0 = f0; e1 = f1; e2 = f2; e3 = f3;
                e4 = f4; e5 = f5; e6 = f6; e7 = f7;
                c0 = d0; c1 = d1; c2 = d2; c3 = d3;
                c4 = d4; c5 = d5; c6 = d6; c7 = d7;
            }
            float v;
            v = __int_as_float(e0.y); acc.x = fmaf(v, c0.x, acc.x); acc.y = fmaf(v, c0.y, acc.y);
            v = __int_as_float(e1.y); acc.x = fmaf(v, c1.x, acc.x); acc.y = fmaf(v, c1.y, acc.y);
            v = __int_as_float(e2.y); acc.x = fmaf(v, c2.x, acc.x); acc.y = fmaf(v, c2.y, acc.y);
            v = __int_as_float(e3.y); acc.x = fmaf(v, c3.x, acc.x); acc.y = fmaf(v, c3.y, acc.y);
            v = __int_as_float(e4.y); acc.x = fmaf(v, c4.x, acc.x); acc.y = fmaf(v, c4.y, acc.y);
            v = __int_as_float(e5.y); acc.x = fmaf(v, c5.x, acc.x); acc.y = fmaf(v, c5.y, acc.y);
            v = __int_as_float(e6.y); acc.x = fmaf(v, c6.x, acc.x); acc.y = fmaf(v, c6.y, acc.y);
            v = __int_as_float(e7.y); acc.x = fmaf(v, c7.x, acc.x); acc.y = fmaf(v, c7.y, acc.y);
        }
        // overflow edges beyond STAGE (statistically never; correctness path)
        for (int q = STAGE; q < Mtot; ++q) {
            unsigned long long p = pairs[cstart + q];
            if ((int)(p & (RPB - 1)) == rl) {
                unsigned lo = (unsigned)(p & 0xffffffffu);
                float v = __int_as_float((int)(p >> 32));
                float2 bv = *reinterpret_cast<const float2*>(
                    bl + (int)((lo & 0xffffffc0u) << 3));
                acc.x = fmaf(v, bv.x, acc.x);  acc.y = fmaf(v, bv.y, acc.y);
            }
        }
        *reinterpret_cast<float2*>(out + (size_t)rg * DIM + lane * 2) = acc;
    }
}

extern "C" void kernel_launch(void* const* d_in, const int* in_sizes, int n_in,
                              void* d_out, int out_size, void* d_ws, size_t ws_size,
                              hipStream_t stream)
{
    const int*   indices = (const int*)d_in[0];    // [2, E]: rows then cols
    const float* vals    = (const float*)d_in[1];  // [E]
    const float* b       = (const float*)d_in[2];  // [N, 128]
    float*       out     = (float*)d_out;          // [N, 128]

    const int E = in_sizes[1];
    const int N = in_sizes[2] / DIM;
    const int* rows = indices;
    const int* cols = indices + E;

    const int NB = (N + RPB - 1) / RPB;            // buckets

    size_t pairs_bytes = (size_t)E * 8;
    size_t needed = pairs_bytes + ((size_t)NB * 3 + 1) * 4;

    if (ws_size < needed || NB > MAXNB || NB < 1 || E < 1) {
        hipMemsetAsync(d_out, 0, (size_t)out_size * sizeof(float), stream);
        if (E >= 1) {
            const long long total = (long long)E * 32;
            const int grid = (int)((total + 255) / 256);
            spmm_atomic_kernel<<<grid, 256, 0, stream>>>(rows, cols, vals, b, out, E);
        }
        return;
    }

    unsigned long long* pairs = (unsigned long long*)d_ws;
    int* ccount   = (int*)((char*)d_ws + pairs_bytes);
    int* coffsets = ccount + NB;
    int* ccursor  = coffsets + (NB + 1);

    hipMemsetAsync(ccount, 0, (size_t)NB * sizeof(int), stream);
    coarse_count_kernel<<<NCH, 256, 0, stream>>>(rows, ccount, E);
    coarse_scan_kernel<<<1, 1024, 0, stream>>>(ccount, coffsets, ccursor, NB, E);
    partition_kernel<<<NCH, 256, 0, stream>>>(rows, cols, vals, ccursor, pairs, E);
    bucket_accum_kernel<<<NB, 256, 0, stream>>>(coffsets, pairs, b, out, N);
}